// Round 1
// baseline (303.760 us; speedup 1.0000x reference)
//
#include <hip/hip_runtime.h>
#include <math.h>

constexpr int D  = 512;
constexpr int H  = 8;
constexpr int DH = 64;
constexpr int B  = 64;
constexpr int NF = 16384;
constexpr int NO = 8192;
constexpr int NT = NF + NO;
constexpr float EPS = 1e-5f;

// ---------------- q = ps @ Wq + bq  (64x512) ----------------
__global__ __launch_bounds__(256) void k_qproj(const float* __restrict__ ps,
                                               const float* __restrict__ Wq,
                                               const float* __restrict__ bq,
                                               float* __restrict__ q) {
  __shared__ float row[D];
  int b = blockIdx.x;
  for (int e = threadIdx.x; e < D; e += 256) row[e] = ps[b * D + e];
  __syncthreads();
  for (int c = threadIdx.x; c < D; c += 256) {
    float acc = bq[c];
    for (int e = 0; e < D; ++e) acc += row[e] * Wq[e * D + c];
    q[b * D + c] = acc;
  }
}

// ------- Pk[b,h,e] = sum_{c in head h} Wk[e,c]*q[b,c]; qbk[b,h] = sum bk[c]*q[b,c]
__global__ __launch_bounds__(256) void k_pkproj(const float* __restrict__ q,
                                                const float* __restrict__ Wk,
                                                const float* __restrict__ bk,
                                                float* __restrict__ Pk,
                                                float* __restrict__ qbk) {
  int b = blockIdx.x, h = blockIdx.y;
  __shared__ float qs[DH];
  __shared__ float bks[DH];
  int t = threadIdx.x;
  if (t < DH) { qs[t] = q[b * D + h * DH + t]; bks[t] = bk[h * DH + t]; }
  __syncthreads();
  for (int e = t; e < D; e += 256) {
    float acc = 0.f;
    #pragma unroll 8
    for (int j = 0; j < DH; ++j) acc += Wk[(size_t)e * D + h * DH + j] * qs[j];
    Pk[((size_t)b * H + h) * D + e] = acc;
  }
  if (t == 0) {
    float s = 0.f;
    for (int j = 0; j < DH; ++j) s += bks[j] * qs[j];
    qbk[b * H + h] = s;
  }
}

// ------- segment boundaries via binary search (batches are sorted runs) -------
__global__ void k_bounds(const int* __restrict__ fb, const int* __restrict__ ob,
                         int* __restrict__ fstart, int* __restrict__ ostart) {
  int t = threadIdx.x;
  if (t <= B) {
    int lo = 0, hi = NF;
    while (lo < hi) { int mid = (lo + hi) >> 1; if (fb[mid] < t) lo = mid + 1; else hi = mid; }
    fstart[t] = lo;
  } else if (t >= 128 && t <= 128 + B) {
    int v = t - 128;
    int lo = 0, hi = NO;
    while (lo < hi) { int mid = (lo + hi) >> 1; if (ob[mid] < v) lo = mid + 1; else hi = mid; }
    ostart[v] = lo;
  }
}

// ------- scores[n,h] = (nodes[n]·Pk[seg,h] + qbk[seg,h]) / 8 ;  wave per node -------
__global__ __launch_bounds__(256) void k_scores(const float* __restrict__ hf,
                                                const float* __restrict__ ho,
                                                const int* __restrict__ fb,
                                                const int* __restrict__ ob,
                                                const float* __restrict__ Pk,
                                                const float* __restrict__ qbk,
                                                float* __restrict__ scores) {
  int lane = threadIdx.x & 63;
  int n = blockIdx.x * 4 + (threadIdx.x >> 6);
  int b; const float* row;
  if (n < NF) { b = fb[n]; row = hf + (size_t)n * D; }
  else        { b = ob[n - NF]; row = ho + (size_t)(n - NF) * D; }
  const float4* r4 = (const float4*)row;
  float4 x0 = r4[lane * 2], x1 = r4[lane * 2 + 1];
  float acc[H];
  #pragma unroll
  for (int h = 0; h < H; ++h) {
    const float4* p4 = (const float4*)(Pk + ((size_t)b * H + h) * D) + lane * 2;
    float4 p0 = p4[0], p1 = p4[1];
    acc[h] = x0.x * p0.x + x0.y * p0.y + x0.z * p0.z + x0.w * p0.w +
             x1.x * p1.x + x1.y * p1.y + x1.z * p1.z + x1.w * p1.w;
  }
  #pragma unroll
  for (int h = 0; h < H; ++h) {
    float v = acc[h];
    #pragma unroll
    for (int off = 32; off; off >>= 1) v += __shfl_xor(v, off);
    if (lane == h) scores[(size_t)n * H + h] = (v + qbk[b * H + h]) * 0.125f;
  }
}

// ------- per (b,h): segment max, e = exp(s-m), denom -------
__global__ __launch_bounds__(512) void k_segsoftmax(const float* __restrict__ scores,
                                                    const int* __restrict__ fstart,
                                                    const int* __restrict__ ostart,
                                                    float* __restrict__ evals,
                                                    float* __restrict__ denom) {
  int b = blockIdx.x;
  int h = threadIdx.x >> 6, lane = threadIdx.x & 63;
  int f0 = fstart[b], f1 = fstart[b + 1];
  int o0 = ostart[b], o1 = ostart[b + 1];
  float m = -1e30f;
  for (int i = f0 + lane; i < f1; i += 64) m = fmaxf(m, scores[(size_t)i * H + h]);
  for (int i = o0 + lane; i < o1; i += 64) m = fmaxf(m, scores[(size_t)(NF + i) * H + h]);
  #pragma unroll
  for (int off = 32; off; off >>= 1) m = fmaxf(m, __shfl_xor(m, off));
  float s = 0.f;
  for (int i = f0 + lane; i < f1; i += 64) {
    float e = expf(scores[(size_t)i * H + h] - m);
    evals[(size_t)i * H + h] = e; s += e;
  }
  for (int i = o0 + lane; i < o1; i += 64) {
    float e = expf(scores[(size_t)(NF + i) * H + h] - m);
    evals[(size_t)(NF + i) * H + h] = e; s += e;
  }
  #pragma unroll
  for (int off = 32; off; off >>= 1) s += __shfl_xor(s, off);
  if (lane == 0) denom[b * H + h] = s;
}

__global__ void k_zeroT(float* __restrict__ T) {
  int i = blockIdx.x * blockDim.x + threadIdx.x;
  if (i < B * H * D) T[i] = 0.f;
}

// ------- T[b,h,e] = sum_{n in seg b} e[n,h]*nodes[n,e] -------
__global__ __launch_bounds__(512) void k_Taccum(const float* __restrict__ hf,
                                                const float* __restrict__ ho,
                                                const int* __restrict__ fstart,
                                                const int* __restrict__ ostart,
                                                const float* __restrict__ evals,
                                                float* __restrict__ T) {
  int b = blockIdx.x, chunk = blockIdx.y;
  int e = threadIdx.x;
  int f0 = fstart[b], flen = fstart[b + 1] - f0;
  int o0 = ostart[b], olen = ostart[b + 1] - o0;
  int L = flen + olen;
  float acc[8] = {0.f, 0.f, 0.f, 0.f, 0.f, 0.f, 0.f, 0.f};
  for (int idx = chunk; idx < L; idx += 8) {
    int n; const float* row;
    if (idx < flen) { n = f0 + idx; row = hf + (size_t)n * D; }
    else            { n = NF + o0 + (idx - flen); row = ho + (size_t)(o0 + idx - flen) * D; }
    float x = row[e];
    const float4* ev = (const float4*)(evals + (size_t)n * H);
    float4 e0 = ev[0], e1 = ev[1];
    acc[0] += e0.x * x; acc[1] += e0.y * x; acc[2] += e0.z * x; acc[3] += e0.w * x;
    acc[4] += e1.x * x; acc[5] += e1.y * x; acc[6] += e1.z * x; acc[7] += e1.w * x;
  }
  #pragma unroll
  for (int h = 0; h < H; ++h) atomicAdd(&T[((size_t)b * H + h) * D + e], acc[h]);
}

// ------- attn = (T@Wv)/denom + bv ; x = attn@Wo + bo + ps ; fs = LN(x) -------
__global__ __launch_bounds__(256) void k_attn_fs(const float* __restrict__ T,
                                                 const float* __restrict__ denom,
                                                 const float* __restrict__ Wv,
                                                 const float* __restrict__ bv,
                                                 const float* __restrict__ Wo,
                                                 const float* __restrict__ bo,
                                                 const float* __restrict__ ps,
                                                 float* __restrict__ fs_out) {
  __shared__ float Ts[H * D];
  __shared__ float attn[D];
  __shared__ float redS[4], redQ[4];
  __shared__ float sMean, sInv;
  int b = blockIdx.x, t = threadIdx.x;
  for (int i = t; i < H * D; i += 256) Ts[i] = T[(size_t)b * H * D + i];
  __syncthreads();
  for (int c = t; c < D; c += 256) {
    int h = c >> 6;
    float acc = 0.f;
    for (int e = 0; e < D; ++e) acc += Ts[h * D + e] * Wv[(size_t)e * D + c];
    attn[c] = acc / denom[b * H + h] + bv[c];
  }
  __syncthreads();
  float xv[2];
  #pragma unroll
  for (int ci = 0; ci < 2; ++ci) {
    int c = t + ci * 256;
    float acc = bo[c] + ps[(size_t)b * D + c];
    for (int e = 0; e < D; ++e) acc += attn[e] * Wo[(size_t)e * D + c];
    xv[ci] = acc;
  }
  float s = xv[0] + xv[1], sq = xv[0] * xv[0] + xv[1] * xv[1];
  int wave = t >> 6, lane = t & 63;
  #pragma unroll
  for (int off = 32; off; off >>= 1) { s += __shfl_xor(s, off); sq += __shfl_xor(sq, off); }
  if (lane == 0) { redS[wave] = s; redQ[wave] = sq; }
  __syncthreads();
  if (t == 0) {
    float S = redS[0] + redS[1] + redS[2] + redS[3];
    float Q = redQ[0] + redQ[1] + redQ[2] + redQ[3];
    float mean = S * (1.f / D);
    float var = Q * (1.f / D) - mean * mean;
    sMean = mean; sInv = rsqrtf(var + EPS);
  }
  __syncthreads();
  #pragma unroll
  for (int ci = 0; ci < 2; ++ci) {
    int c = t + ci * 256;
    fs_out[(size_t)b * D + c] = (xv[ci] - sMean) * sInv;
  }
}

// ------- gate = sigmoid(hf @ Wg + bg), written into out[0..NF*D) -------
__global__ __launch_bounds__(256) void k_gate_gemm(const float* __restrict__ hf,
                                                   const float* __restrict__ Wg,
                                                   const float* __restrict__ bg,
                                                   float* __restrict__ gate_out) {
  __shared__ float As[32][68];  // transposed A tile, padded (stride 272B, 16B-aligned)
  __shared__ float Bs[32][64];
  int tid = threadIdx.x;
  int tx = tid & 15, ty = tid >> 4;
  int rowBase = blockIdx.x * 64, colBase = blockIdx.y * 64;
  float acc[4][4] = {};
  for (int k0 = 0; k0 < D; k0 += 32) {
    #pragma unroll
    for (int i = 0; i < 2; ++i) {
      int idx = tid + i * 256;
      int m = idx >> 3, kq = idx & 7;
      float4 v = *(const float4*)&hf[(size_t)(rowBase + m) * D + k0 + kq * 4];
      As[kq * 4 + 0][m] = v.x; As[kq * 4 + 1][m] = v.y;
      As[kq * 4 + 2][m] = v.z; As[kq * 4 + 3][m] = v.w;
    }
    #pragma unroll
    for (int i = 0; i < 2; ++i) {
      int idx = tid + i * 256;
      int k = idx >> 4, cq = idx & 15;
      float4 v = *(const float4*)&Wg[(size_t)(k0 + k) * D + colBase + cq * 4];
      *(float4*)&Bs[k][cq * 4] = v;
    }
    __syncthreads();
    #pragma unroll
    for (int k = 0; k < 32; ++k) {
      float4 av = *(const float4*)&As[k][ty * 4];
      float4 bw = *(const float4*)&Bs[k][tx * 4];
      float ar[4] = {av.x, av.y, av.z, av.w};
      float br[4] = {bw.x, bw.y, bw.z, bw.w};
      #pragma unroll
      for (int i = 0; i < 4; ++i)
        #pragma unroll
        for (int j = 0; j < 4; ++j)
          acc[i][j] += ar[i] * br[j];
    }
    __syncthreads();
  }
  #pragma unroll
  for (int i = 0; i < 4; ++i) {
    int r = rowBase + ty * 4 + i;
    int c0 = colBase + tx * 4;
    float4 o;
    o.x = 1.f / (1.f + expf(-(acc[i][0] + bg[c0 + 0])));
    o.y = 1.f / (1.f + expf(-(acc[i][1] + bg[c0 + 1])));
    o.z = 1.f / (1.f + expf(-(acc[i][2] + bg[c0 + 2])));
    o.w = 1.f / (1.f + expf(-(acc[i][3] + bg[c0 + 3])));
    *(float4*)&gate_out[(size_t)r * D + c0] = o;
  }
}

// ------- hf_new = LN(hf + gate * (alpha * fs[fb])) ; gate read in-place from out -------
__global__ __launch_bounds__(256) void k_final(const float* __restrict__ hf,
                                               const int* __restrict__ fb,
                                               const float* __restrict__ alpha,
                                               const float* __restrict__ fs,
                                               float* __restrict__ out) {
  __shared__ float redS[4], redQ[4];
  __shared__ float sMean, sInv;
  int f = blockIdx.x, t = threadIdx.x;
  int b = fb[f];
  float xv[2];
  #pragma unroll
  for (int ci = 0; ci < 2; ++ci) {
    int c = t + ci * 256;
    float g = out[(size_t)f * D + c];
    xv[ci] = hf[(size_t)f * D + c] + g * (alpha[c] * fs[(size_t)b * D + c]);
  }
  float s = xv[0] + xv[1], sq = xv[0] * xv[0] + xv[1] * xv[1];
  int wave = t >> 6, lane = t & 63;
  #pragma unroll
  for (int off = 32; off; off >>= 1) { s += __shfl_xor(s, off); sq += __shfl_xor(sq, off); }
  if (lane == 0) { redS[wave] = s; redQ[wave] = sq; }
  __syncthreads();
  if (t == 0) {
    float S = redS[0] + redS[1] + redS[2] + redS[3];
    float Q = redQ[0] + redQ[1] + redQ[2] + redQ[3];
    float mean = S * (1.f / D);
    float var = Q * (1.f / D) - mean * mean;
    sMean = mean; sInv = rsqrtf(var + EPS);
  }
  __syncthreads();
  #pragma unroll
  for (int ci = 0; ci < 2; ++ci) {
    int c = t + ci * 256;
    out[(size_t)f * D + c] = (xv[ci] - sMean) * sInv;
  }
}

extern "C" void kernel_launch(void* const* d_in, const int* in_sizes, int n_in,
                              void* d_out, int out_size, void* d_ws, size_t ws_size,
                              hipStream_t stream) {
  const float* hf    = (const float*)d_in[0];
  const float* ho    = (const float*)d_in[1];
  const float* ps    = (const float*)d_in[2];
  const int*   fb    = (const int*)d_in[3];
  const int*   ob    = (const int*)d_in[4];
  const float* Wq    = (const float*)d_in[5];
  const float* bq    = (const float*)d_in[6];
  const float* Wk    = (const float*)d_in[7];
  const float* bk    = (const float*)d_in[8];
  const float* Wv    = (const float*)d_in[9];
  const float* bv    = (const float*)d_in[10];
  const float* Wo    = (const float*)d_in[11];
  const float* bo    = (const float*)d_in[12];
  const float* Wg    = (const float*)d_in[13];
  const float* bg    = (const float*)d_in[14];
  const float* alpha = (const float*)d_in[15];

  float* out    = (float*)d_out;
  float* fs_out = out + (size_t)NF * D;

  float* ws     = (float*)d_ws;
  float* q      = ws;                      // B*D
  float* Pk     = q + B * D;               // B*H*D
  float* qbk    = Pk + B * H * D;          // B*H
  float* scores = qbk + B * H;             // NT*H
  float* evals  = scores + (size_t)NT * H; // NT*H
  float* denom  = evals + (size_t)NT * H;  // B*H
  float* T      = denom + B * H;           // B*H*D
  int* fstart   = (int*)(T + B * H * D);   // B+1
  int* ostart   = fstart + (B + 1);        // B+1

  k_qproj<<<B, 256, 0, stream>>>(ps, Wq, bq, q);
  k_pkproj<<<dim3(B, H), 256, 0, stream>>>(q, Wk, bk, Pk, qbk);
  k_bounds<<<1, 256, 0, stream>>>(fb, ob, fstart, ostart);
  k_scores<<<NT / 4, 256, 0, stream>>>(hf, ho, fb, ob, Pk, qbk, scores);
  k_segsoftmax<<<B, 512, 0, stream>>>(scores, fstart, ostart, evals, denom);
  k_zeroT<<<(B * H * D + 255) / 256, 256, 0, stream>>>(T);
  k_Taccum<<<dim3(B, 8), 512, 0, stream>>>(hf, ho, fstart, ostart, evals, T);
  k_attn_fs<<<B, 256, 0, stream>>>(T, denom, Wv, bv, Wo, bo, ps, fs_out);
  k_gate_gemm<<<dim3(NF / 64, D / 64), 256, 0, stream>>>(hf, Wg, bg, out);
  k_final<<<NF, 256, 0, stream>>>(hf, fb, alpha, fs_out, out);
}

// Round 2
// 240.295 us; speedup vs baseline: 1.2641x; 1.2641x over previous
//
#include <hip/hip_runtime.h>
#include <hip/hip_bf16.h>
#include <math.h>

constexpr int D  = 512;
constexpr int H  = 8;
constexpr int DH = 64;
constexpr int B  = 64;
constexpr int NF = 16384;
constexpr int NO = 8192;
constexpr int NT = NF + NO;
constexpr float EPS = 1e-5f;

typedef short short8 __attribute__((ext_vector_type(8)));
typedef float f32x4 __attribute__((ext_vector_type(4)));
typedef unsigned short ushort;
typedef ushort ushort8v __attribute__((ext_vector_type(8)));

__device__ __forceinline__ ushort f2bf(float f) {
  unsigned int x = __float_as_uint(f);
  x += 0x7FFF + ((x >> 16) & 1);   // RNE (inputs finite)
  return (ushort)(x >> 16);
}
__device__ __forceinline__ float bf2f(ushort u) {
  return __uint_as_float(((unsigned int)u) << 16);
}

// ---------------- q = ps @ Wq + bq  (64x512) ----------------
__global__ __launch_bounds__(256) void k_qproj(const float* __restrict__ ps,
                                               const float* __restrict__ Wq,
                                               const float* __restrict__ bq,
                                               float* __restrict__ q) {
  __shared__ float row[D];
  int b = blockIdx.x;
  for (int e = threadIdx.x; e < D; e += 256) row[e] = ps[b * D + e];
  __syncthreads();
  for (int c = threadIdx.x; c < D; c += 256) {
    float acc = bq[c];
    for (int e = 0; e < D; ++e) acc += row[e] * Wq[e * D + c];
    q[b * D + c] = acc;
  }
}

// ------- Pk[b,h,e] = sum_{c in head h} Wk[e,c]*q[b,c]; qbk[b,h] = sum bk[c]*q[b,c]
__global__ __launch_bounds__(256) void k_pkproj(const float* __restrict__ q,
                                                const float* __restrict__ Wk,
                                                const float* __restrict__ bk,
                                                float* __restrict__ Pk,
                                                float* __restrict__ qbk) {
  int b = blockIdx.x, h = blockIdx.y;
  __shared__ float qs[DH];
  __shared__ float bks[DH];
  int t = threadIdx.x;
  if (t < DH) { qs[t] = q[b * D + h * DH + t]; bks[t] = bk[h * DH + t]; }
  __syncthreads();
  for (int e = t; e < D; e += 256) {
    float acc = 0.f;
    #pragma unroll 8
    for (int j = 0; j < DH; ++j) acc += Wk[(size_t)e * D + h * DH + j] * qs[j];
    Pk[((size_t)b * H + h) * D + e] = acc;
  }
  if (t == 0) {
    float s = 0.f;
    for (int j = 0; j < DH; ++j) s += bks[j] * qs[j];
    qbk[b * H + h] = s;
  }
}

// ------- segment boundaries via binary search (batches are sorted runs) -------
__global__ void k_bounds(const int* __restrict__ fb, const int* __restrict__ ob,
                         int* __restrict__ fstart, int* __restrict__ ostart) {
  int t = threadIdx.x;
  if (t <= B) {
    int lo = 0, hi = NF;
    while (lo < hi) { int mid = (lo + hi) >> 1; if (fb[mid] < t) lo = mid + 1; else hi = mid; }
    fstart[t] = lo;
  } else if (t >= 128 && t <= 128 + B) {
    int v = t - 128;
    int lo = 0, hi = NO;
    while (lo < hi) { int mid = (lo + hi) >> 1; if (ob[mid] < v) lo = mid + 1; else hi = mid; }
    ostart[v] = lo;
  }
}

// ------- scores[n,h] = (nodes[n]·Pk[seg,h] + qbk[seg,h]) / 8 ;  wave per node -------
__global__ __launch_bounds__(256) void k_scores(const float* __restrict__ hf,
                                                const float* __restrict__ ho,
                                                const int* __restrict__ fb,
                                                const int* __restrict__ ob,
                                                const float* __restrict__ Pk,
                                                const float* __restrict__ qbk,
                                                float* __restrict__ scores) {
  int lane = threadIdx.x & 63;
  int n = blockIdx.x * 4 + (threadIdx.x >> 6);
  int b; const float* row;
  if (n < NF) { b = fb[n]; row = hf + (size_t)n * D; }
  else        { b = ob[n - NF]; row = ho + (size_t)(n - NF) * D; }
  const float4* r4 = (const float4*)row;
  float4 x0 = r4[lane * 2], x1 = r4[lane * 2 + 1];
  float acc[H];
  #pragma unroll
  for (int h = 0; h < H; ++h) {
    const float4* p4 = (const float4*)(Pk + ((size_t)b * H + h) * D) + lane * 2;
    float4 p0 = p4[0], p1 = p4[1];
    acc[h] = x0.x * p0.x + x0.y * p0.y + x0.z * p0.z + x0.w * p0.w +
             x1.x * p1.x + x1.y * p1.y + x1.z * p1.z + x1.w * p1.w;
  }
  #pragma unroll
  for (int h = 0; h < H; ++h) {
    float v = acc[h];
    #pragma unroll
    for (int off = 32; off; off >>= 1) v += __shfl_xor(v, off);
    if (lane == h) scores[(size_t)n * H + h] = (v + qbk[b * H + h]) * 0.125f;
  }
}

// ------- per (b,h): segment max, e = exp(s-m), denom -------
__global__ __launch_bounds__(512) void k_segsoftmax(const float* __restrict__ scores,
                                                    const int* __restrict__ fstart,
                                                    const int* __restrict__ ostart,
                                                    float* __restrict__ evals,
                                                    float* __restrict__ denom) {
  int b = blockIdx.x;
  int h = threadIdx.x >> 6, lane = threadIdx.x & 63;
  int f0 = fstart[b], f1 = fstart[b + 1];
  int o0 = ostart[b], o1 = ostart[b + 1];
  float m = -1e30f;
  for (int i = f0 + lane; i < f1; i += 64) m = fmaxf(m, scores[(size_t)i * H + h]);
  for (int i = o0 + lane; i < o1; i += 64) m = fmaxf(m, scores[(size_t)(NF + i) * H + h]);
  #pragma unroll
  for (int off = 32; off; off >>= 1) m = fmaxf(m, __shfl_xor(m, off));
  float s = 0.f;
  for (int i = f0 + lane; i < f1; i += 64) {
    float e = expf(scores[(size_t)i * H + h] - m);
    evals[(size_t)i * H + h] = e; s += e;
  }
  for (int i = o0 + lane; i < o1; i += 64) {
    float e = expf(scores[(size_t)(NF + i) * H + h] - m);
    evals[(size_t)(NF + i) * H + h] = e; s += e;
  }
  #pragma unroll
  for (int off = 32; off; off >>= 1) s += __shfl_xor(s, off);
  if (lane == 0) denom[b * H + h] = s;
}

__global__ void k_zeroT(float* __restrict__ T) {
  int i = blockIdx.x * blockDim.x + threadIdx.x;
  if (i < B * H * D) T[i] = 0.f;
}

// ------- T[b,h,e] = sum_{n in seg b} e[n,h]*nodes[n,e] -------
__global__ __launch_bounds__(512) void k_Taccum(const float* __restrict__ hf,
                                                const float* __restrict__ ho,
                                                const int* __restrict__ fstart,
                                                const int* __restrict__ ostart,
                                                const float* __restrict__ evals,
                                                float* __restrict__ T) {
  int b = blockIdx.x, chunk = blockIdx.y;
  int e = threadIdx.x;
  int f0 = fstart[b], flen = fstart[b + 1] - f0;
  int o0 = ostart[b], olen = ostart[b + 1] - o0;
  int L = flen + olen;
  float acc[8] = {0.f, 0.f, 0.f, 0.f, 0.f, 0.f, 0.f, 0.f};
  for (int idx = chunk; idx < L; idx += 8) {
    int n; const float* row;
    if (idx < flen) { n = f0 + idx; row = hf + (size_t)n * D; }
    else            { n = NF + o0 + (idx - flen); row = ho + (size_t)(o0 + idx - flen) * D; }
    float x = row[e];
    const float4* ev = (const float4*)(evals + (size_t)n * H);
    float4 e0 = ev[0], e1 = ev[1];
    acc[0] += e0.x * x; acc[1] += e0.y * x; acc[2] += e0.z * x; acc[3] += e0.w * x;
    acc[4] += e1.x * x; acc[5] += e1.y * x; acc[6] += e1.z * x; acc[7] += e1.w * x;
  }
  #pragma unroll
  for (int h = 0; h < H; ++h) atomicAdd(&T[((size_t)b * H + h) * D + e], acc[h]);
}

// ------- attn = (T@Wv)/denom + bv ; x = attn@Wo + bo + ps ; fs = LN(x) -------
__global__ __launch_bounds__(256) void k_attn_fs(const float* __restrict__ T,
                                                 const float* __restrict__ denom,
                                                 const float* __restrict__ Wv,
                                                 const float* __restrict__ bv,
                                                 const float* __restrict__ Wo,
                                                 const float* __restrict__ bo,
                                                 const float* __restrict__ ps,
                                                 float* __restrict__ fs_out) {
  __shared__ float Ts[H * D];
  __shared__ float attn[D];
  __shared__ float redS[4], redQ[4];
  __shared__ float sMean, sInv;
  int b = blockIdx.x, t = threadIdx.x;
  for (int i = t; i < H * D; i += 256) Ts[i] = T[(size_t)b * H * D + i];
  __syncthreads();
  for (int c = t; c < D; c += 256) {
    int h = c >> 6;
    float acc = 0.f;
    for (int e = 0; e < D; ++e) acc += Ts[h * D + e] * Wv[(size_t)e * D + c];
    attn[c] = acc / denom[b * H + h] + bv[c];
  }
  __syncthreads();
  float xv[2];
  #pragma unroll
  for (int ci = 0; ci < 2; ++ci) {
    int c = t + ci * 256;
    float acc = bo[c] + ps[(size_t)b * D + c];
    for (int e = 0; e < D; ++e) acc += attn[e] * Wo[(size_t)e * D + c];
    xv[ci] = acc;
  }
  float s = xv[0] + xv[1], sq = xv[0] * xv[0] + xv[1] * xv[1];
  int wave = t >> 6, lane = t & 63;
  #pragma unroll
  for (int off = 32; off; off >>= 1) { s += __shfl_xor(s, off); sq += __shfl_xor(sq, off); }
  if (lane == 0) { redS[wave] = s; redQ[wave] = sq; }
  __syncthreads();
  if (t == 0) {
    float S = redS[0] + redS[1] + redS[2] + redS[3];
    float Q = redQ[0] + redQ[1] + redQ[2] + redQ[3];
    float mean = S * (1.f / D);
    float var = Q * (1.f / D) - mean * mean;
    sMean = mean; sInv = rsqrtf(var + EPS);
  }
  __syncthreads();
  #pragma unroll
  for (int ci = 0; ci < 2; ++ci) {
    int c = t + ci * 256;
    fs_out[(size_t)b * D + c] = (xv[ci] - sMean) * sInv;
  }
}

// ------- Wgt[c][k] = bf16(Wg[k][c]) -------
__global__ __launch_bounds__(256) void k_prepW(const float* __restrict__ Wg,
                                               ushort* __restrict__ Wgt) {
  __shared__ float tile[32][33];
  int bx = blockIdx.x, by = blockIdx.y;
  int tx = threadIdx.x & 31, ty = threadIdx.x >> 5;  // ty: 0..7
  #pragma unroll
  for (int i = 0; i < 4; ++i)
    tile[ty + i * 8][tx] = Wg[(size_t)(by * 32 + ty + i * 8) * D + bx * 32 + tx];
  __syncthreads();
  #pragma unroll
  for (int i = 0; i < 4; ++i)
    Wgt[(size_t)(bx * 32 + ty + i * 8) * D + by * 32 + tx] = f2bf(tile[tx][ty + i * 8]);
}

// ------- fused: gate = sigmoid(hf@Wg+bg); out = LN(hf + gate*(alpha*fs[fb])) -------
// block: 64 rows x 512 cols, 8 waves (each 64x64), mfma_f32_16x16x32_bf16, no operand LDS.
__global__ __launch_bounds__(512) void k_gate_ln(const float* __restrict__ hf,
                                                 const ushort* __restrict__ Wgt,
                                                 const float* __restrict__ bg,
                                                 const float* __restrict__ alpha,
                                                 const float* __restrict__ fs,
                                                 const int* __restrict__ fb,
                                                 float* __restrict__ out) {
  __shared__ ushort gls[64][544];   // bf16 gate tile, col-block XOR swizzle
  const int tid = threadIdx.x;
  const int lane = tid & 63, w = tid >> 6;
  const int rowBase = blockIdx.x * 64;
  const int lrow = lane & 15, kg = lane >> 4;

  f32x4 acc[4][4] = {};
  const float*  Ap = hf  + (size_t)(rowBase + lrow) * D + kg * 8;
  const ushort* Bp = Wgt + (size_t)(w * 64 + lrow) * D + kg * 8;

  for (int k0 = 0; k0 < D; k0 += 32) {
    short8 a[4], bfr[4];
    #pragma unroll
    for (int m = 0; m < 4; ++m) {
      const float* p = Ap + (size_t)m * 16 * D + k0;
      float4 f0 = *(const float4*)p;
      float4 f1 = *(const float4*)(p + 4);
      union { short8 v; ushort u[8]; } ua;
      ua.u[0] = f2bf(f0.x); ua.u[1] = f2bf(f0.y); ua.u[2] = f2bf(f0.z); ua.u[3] = f2bf(f0.w);
      ua.u[4] = f2bf(f1.x); ua.u[5] = f2bf(f1.y); ua.u[6] = f2bf(f1.z); ua.u[7] = f2bf(f1.w);
      a[m] = ua.v;
    }
    #pragma unroll
    for (int n = 0; n < 4; ++n)
      bfr[n] = *(const short8*)(Bp + (size_t)n * 16 * D + k0);
    #pragma unroll
    for (int m = 0; m < 4; ++m)
      #pragma unroll
      for (int n = 0; n < 4; ++n)
        acc[m][n] = __builtin_amdgcn_mfma_f32_16x16x32_bf16(a[m], bfr[n], acc[m][n], 0, 0, 0);
  }

  // phase 1: sigmoid -> swizzled bf16 LDS.  C/D map: col=lane&15, row=(lane>>4)*4+reg
  #pragma unroll
  for (int n = 0; n < 4; ++n) {
    int col = w * 64 + n * 16 + lrow;
    float bgv = bg[col];
    int sblk = (col >> 3) ^ w;                 // (colblk>>3)==w for this wave's cols
    #pragma unroll
    for (int m = 0; m < 4; ++m) {
      #pragma unroll
      for (int r = 0; r < 4; ++r) {
        int rib = m * 16 + kg * 4 + r;
        float z = acc[m][n][r] + bgv;
        float g = 1.0f / (1.0f + expf(-z));
        ((ushort*)gls)[rib * 544 + sblk * 8 + (lrow & 7)] = f2bf(g);
      }
    }
  }
  __syncthreads();

  // phase 2: per-row residual + LN, vectorized
  const int row = tid >> 3, cg = tid & 7;      // 8 threads per row, 64 cols each
  const int grow = rowBase + row;
  const int bidx = fb[grow];
  const float* hfr = hf + (size_t)grow * D + cg * 64;
  const float* fsr = fs + (size_t)bidx * D + cg * 64;
  const float* alr = alpha + cg * 64;
  float x[64];
  float s = 0.f, sq = 0.f;
  #pragma unroll
  for (int jb = 0; jb < 8; ++jb) {
    int sblk = (cg * 8 + jb) ^ cg;
    union { ushort8v v; ushort u[8]; } ug;
    ug.v = *(const ushort8v*)((const ushort*)gls + row * 544 + sblk * 8);
    float4 h0 = *(const float4*)(hfr + jb * 8);
    float4 h1 = *(const float4*)(hfr + jb * 8 + 4);
    float4 p0 = *(const float4*)(fsr + jb * 8);
    float4 p1 = *(const float4*)(fsr + jb * 8 + 4);
    float4 a0 = *(const float4*)(alr + jb * 8);
    float4 a1 = *(const float4*)(alr + jb * 8 + 4);
    float hv[8] = {h0.x, h0.y, h0.z, h0.w, h1.x, h1.y, h1.z, h1.w};
    float pv[8] = {p0.x, p0.y, p0.z, p0.w, p1.x, p1.y, p1.z, p1.w};
    float av[8] = {a0.x, a0.y, a0.z, a0.w, a1.x, a1.y, a1.z, a1.w};
    #pragma unroll
    for (int i = 0; i < 8; ++i) {
      float xv = hv[i] + bf2f(ug.u[i]) * (av[i] * pv[i]);
      x[jb * 8 + i] = xv; s += xv; sq += xv * xv;
    }
  }
  #pragma unroll
  for (int off = 1; off < 8; off <<= 1) { s += __shfl_xor(s, off); sq += __shfl_xor(sq, off); }
  float mean = s * (1.f / D);
  float inv = rsqrtf(sq * (1.f / D) - mean * mean + EPS);
  float* op = out + (size_t)grow * D + cg * 64;
  #pragma unroll
  for (int j4 = 0; j4 < 16; ++j4) {
    float4 o = { (x[j4 * 4 + 0] - mean) * inv, (x[j4 * 4 + 1] - mean) * inv,
                 (x[j4 * 4 + 2] - mean) * inv, (x[j4 * 4 + 3] - mean) * inv };
    *(float4*)(op + j4 * 4) = o;
  }
}

extern "C" void kernel_launch(void* const* d_in, const int* in_sizes, int n_in,
                              void* d_out, int out_size, void* d_ws, size_t ws_size,
                              hipStream_t stream) {
  const float* hf    = (const float*)d_in[0];
  const float* ho    = (const float*)d_in[1];
  const float* ps    = (const float*)d_in[2];
  const int*   fb    = (const int*)d_in[3];
  const int*   ob    = (const int*)d_in[4];
  const float* Wq    = (const float*)d_in[5];
  const float* bq    = (const float*)d_in[6];
  const float* Wk    = (const float*)d_in[7];
  const float* bk    = (const float*)d_in[8];
  const float* Wv    = (const float*)d_in[9];
  const float* bv    = (const float*)d_in[10];
  const float* Wo    = (const float*)d_in[11];
  const float* bo    = (const float*)d_in[12];
  const float* Wg    = (const float*)d_in[13];
  const float* bg    = (const float*)d_in[14];
  const float* alpha = (const float*)d_in[15];

  float* out    = (float*)d_out;
  float* fs_out = out + (size_t)NF * D;

  ushort* Wgt   = (ushort*)d_ws;                    // 512KB bf16 Wg^T
  float* ws     = (float*)d_ws + (512 * 512 * 2) / 4;
  float* q      = ws;                      // B*D
  float* Pk     = q + B * D;               // B*H*D
  float* qbk    = Pk + B * H * D;          // B*H
  float* scores = qbk + B * H;             // NT*H
  float* evals  = scores + (size_t)NT * H; // NT*H
  float* denom  = evals + (size_t)NT * H;  // B*H
  float* T      = denom + B * H;           // B*H*D
  int* fstart   = (int*)(T + B * H * D);   // B+1
  int* ostart   = fstart + (B + 1);        // B+1

  k_prepW<<<dim3(16, 16), 256, 0, stream>>>(Wg, Wgt);
  k_qproj<<<B, 256, 0, stream>>>(ps, Wq, bq, q);
  k_pkproj<<<dim3(B, H), 256, 0, stream>>>(q, Wk, bk, Pk, qbk);
  k_bounds<<<1, 256, 0, stream>>>(fb, ob, fstart, ostart);
  k_scores<<<NT / 4, 256, 0, stream>>>(hf, ho, fb, ob, Pk, qbk, scores);
  k_segsoftmax<<<B, 512, 0, stream>>>(scores, fstart, ostart, evals, denom);
  k_zeroT<<<(B * H * D + 255) / 256, 256, 0, stream>>>(T);
  k_Taccum<<<dim3(B, 8), 512, 0, stream>>>(hf, ho, fstart, ostart, evals, T);
  k_attn_fs<<<B, 256, 0, stream>>>(T, denom, Wv, bv, Wo, bo, ps, fs_out);
  k_gate_ln<<<NF / 64, 512, 0, stream>>>(hf, Wgt, bg, alpha, fs_out, fb, out);
}

// Round 3
// 162.110 us; speedup vs baseline: 1.8738x; 1.4823x over previous
//
#include <hip/hip_runtime.h>
#include <hip/hip_bf16.h>
#include <math.h>

constexpr int D  = 512;
constexpr int H  = 8;
constexpr int DH = 64;
constexpr int B  = 64;
constexpr int NF = 16384;
constexpr int NO = 8192;
constexpr int NT = NF + NO;
constexpr float EPS = 1e-5f;
constexpr float LOG2E = 1.4426950408889634f;

typedef short short8 __attribute__((ext_vector_type(8)));
typedef float f32x4 __attribute__((ext_vector_type(4)));
typedef unsigned short ushort;
typedef ushort ushort8v __attribute__((ext_vector_type(8)));
typedef ushort ushort4v __attribute__((ext_vector_type(4)));

__device__ __forceinline__ ushort f2bf(float f) {
  unsigned int x = __float_as_uint(f);
  x += 0x7FFF + ((x >> 16) & 1);   // RNE (inputs finite)
  return (ushort)(x >> 16);
}
__device__ __forceinline__ float bf2f(ushort u) {
  return __uint_as_float(((unsigned int)u) << 16);
}
__device__ __forceinline__ float fast_exp(float x) {   // e^x
  return __builtin_amdgcn_exp2f(x * LOG2E);
}
__device__ __forceinline__ float fast_sigmoid(float z) {
  return __builtin_amdgcn_rcpf(1.0f + __builtin_amdgcn_exp2f(-z * LOG2E));
}

// ---------------- q = ps @ Wq + bq  (64x512), parallel: grid (B,8) ----------------
__global__ __launch_bounds__(256) void k_qproj(const float* __restrict__ ps,
                                               const float* __restrict__ Wq,
                                               const float* __restrict__ bq,
                                               float* __restrict__ q) {
  __shared__ float row[D];
  int b = blockIdx.x, cg = blockIdx.y, t = threadIdx.x;
  for (int i = t; i < D; i += 256) row[i] = ps[(size_t)b * D + i];
  __syncthreads();
  int col = cg * 64 + (t >> 2), eq = t & 3;
  float acc = 0.f;
  const float* wp = Wq + (size_t)(eq * 128) * D + col;
  #pragma unroll 8
  for (int e = 0; e < 128; ++e) acc += row[eq * 128 + e] * wp[(size_t)e * D];
  acc += __shfl_xor(acc, 1); acc += __shfl_xor(acc, 2);
  if (eq == 0) q[(size_t)b * D + col] = acc + bq[col];
}

// ------- Pk[b,h,e] = sum_{c in head h} Wk[e,c]*q[b,c]; qbk[b,h] = sum bk[c]*q[b,c]
__global__ __launch_bounds__(256) void k_pkproj(const float* __restrict__ q,
                                                const float* __restrict__ Wk,
                                                const float* __restrict__ bk,
                                                float* __restrict__ Pk,
                                                float* __restrict__ qbk) {
  int b = blockIdx.x, h = blockIdx.y;
  __shared__ float qs[DH];
  __shared__ float bks[DH];
  int t = threadIdx.x;
  if (t < DH) { qs[t] = q[b * D + h * DH + t]; bks[t] = bk[h * DH + t]; }
  __syncthreads();
  for (int e = t; e < D; e += 256) {
    float acc = 0.f;
    #pragma unroll 8
    for (int j = 0; j < DH; ++j) acc += Wk[(size_t)e * D + h * DH + j] * qs[j];
    Pk[((size_t)b * H + h) * D + e] = acc;
  }
  if (t == 0) {
    float s = 0.f;
    for (int j = 0; j < DH; ++j) s += bks[j] * qs[j];
    qbk[b * H + h] = s;
  }
}

// ------- segment boundaries via binary search (batches are sorted runs) -------
__global__ void k_bounds(const int* __restrict__ fb, const int* __restrict__ ob,
                         int* __restrict__ fstart, int* __restrict__ ostart) {
  int t = threadIdx.x;
  if (t <= B) {
    int lo = 0, hi = NF;
    while (lo < hi) { int mid = (lo + hi) >> 1; if (fb[mid] < t) lo = mid + 1; else hi = mid; }
    fstart[t] = lo;
  } else if (t >= 128 && t <= 128 + B) {
    int v = t - 128;
    int lo = 0, hi = NO;
    while (lo < hi) { int mid = (lo + hi) >> 1; if (ob[mid] < v) lo = mid + 1; else hi = mid; }
    ostart[v] = lo;
  }
}

// ------- scores[n,h] = (nodes[n]·Pk[seg,h] + qbk[seg,h]) / 8 ;  wave per node -------
__global__ __launch_bounds__(256) void k_scores(const float* __restrict__ hf,
                                                const float* __restrict__ ho,
                                                const int* __restrict__ fb,
                                                const int* __restrict__ ob,
                                                const float* __restrict__ Pk,
                                                const float* __restrict__ qbk,
                                                float* __restrict__ scores) {
  int lane = threadIdx.x & 63;
  int n = blockIdx.x * 4 + (threadIdx.x >> 6);
  int b; const float* row;
  if (n < NF) { b = fb[n]; row = hf + (size_t)n * D; }
  else        { b = ob[n - NF]; row = ho + (size_t)(n - NF) * D; }
  const float4* r4 = (const float4*)row;
  float4 x0 = r4[lane * 2], x1 = r4[lane * 2 + 1];
  float acc[H];
  #pragma unroll
  for (int h = 0; h < H; ++h) {
    const float4* p4 = (const float4*)(Pk + ((size_t)b * H + h) * D) + lane * 2;
    float4 p0 = p4[0], p1 = p4[1];
    acc[h] = x0.x * p0.x + x0.y * p0.y + x0.z * p0.z + x0.w * p0.w +
             x1.x * p1.x + x1.y * p1.y + x1.z * p1.z + x1.w * p1.w;
  }
  #pragma unroll
  for (int h = 0; h < H; ++h) {
    float v = acc[h];
    #pragma unroll
    for (int off = 32; off; off >>= 1) v += __shfl_xor(v, off);
    if (lane == h) scores[(size_t)n * H + h] = (v + qbk[b * H + h]) * 0.125f;
  }
}

// ------- per (b,h): segment max, e = exp(s-m), denom -------
__global__ __launch_bounds__(512) void k_segsoftmax(const float* __restrict__ scores,
                                                    const int* __restrict__ fstart,
                                                    const int* __restrict__ ostart,
                                                    float* __restrict__ evals,
                                                    float* __restrict__ denom) {
  int b = blockIdx.x;
  int h = threadIdx.x >> 6, lane = threadIdx.x & 63;
  int f0 = fstart[b], f1 = fstart[b + 1];
  int o0 = ostart[b], o1 = ostart[b + 1];
  float m = -1e30f;
  for (int i = f0 + lane; i < f1; i += 64) m = fmaxf(m, scores[(size_t)i * H + h]);
  for (int i = o0 + lane; i < o1; i += 64) m = fmaxf(m, scores[(size_t)(NF + i) * H + h]);
  #pragma unroll
  for (int off = 32; off; off >>= 1) m = fmaxf(m, __shfl_xor(m, off));
  float s = 0.f;
  for (int i = f0 + lane; i < f1; i += 64) {
    float e = fast_exp(scores[(size_t)i * H + h] - m);
    evals[(size_t)i * H + h] = e; s += e;
  }
  for (int i = o0 + lane; i < o1; i += 64) {
    float e = fast_exp(scores[(size_t)(NF + i) * H + h] - m);
    evals[(size_t)(NF + i) * H + h] = e; s += e;
  }
  #pragma unroll
  for (int off = 32; off; off >>= 1) s += __shfl_xor(s, off);
  if (lane == 0) denom[b * H + h] = s;
}

// ------- T[b,h,e] = sum_{n in seg b} e[n,h]*nodes[n,e] -------
__global__ __launch_bounds__(512) void k_Taccum(const float* __restrict__ hf,
                                                const float* __restrict__ ho,
                                                const int* __restrict__ fstart,
                                                const int* __restrict__ ostart,
                                                const float* __restrict__ evals,
                                                float* __restrict__ T) {
  int b = blockIdx.x, chunk = blockIdx.y;
  int e = threadIdx.x;
  int f0 = fstart[b], flen = fstart[b + 1] - f0;
  int o0 = ostart[b], olen = ostart[b + 1] - o0;
  int L = flen + olen;
  float acc[8] = {0.f, 0.f, 0.f, 0.f, 0.f, 0.f, 0.f, 0.f};
  for (int idx = chunk; idx < L; idx += 8) {
    int n; const float* row;
    if (idx < flen) { n = f0 + idx; row = hf + (size_t)n * D; }
    else            { n = NF + o0 + (idx - flen); row = ho + (size_t)(o0 + idx - flen) * D; }
    float x = row[e];
    const float4* ev = (const float4*)(evals + (size_t)n * H);
    float4 e0 = ev[0], e1 = ev[1];
    acc[0] += e0.x * x; acc[1] += e0.y * x; acc[2] += e0.z * x; acc[3] += e0.w * x;
    acc[4] += e1.x * x; acc[5] += e1.y * x; acc[6] += e1.z * x; acc[7] += e1.w * x;
  }
  #pragma unroll
  for (int h = 0; h < H; ++h) atomicAdd(&T[((size_t)b * H + h) * D + e], acc[h]);
}

// ------- attn[b,c] = (T[b,h(c),:]·Wv[:,c])/denom[b,h] + bv[c]; grid (B,H) -------
__global__ __launch_bounds__(256) void k_attn(const float* __restrict__ T,
                                              const float* __restrict__ denom,
                                              const float* __restrict__ Wv,
                                              const float* __restrict__ bv,
                                              float* __restrict__ attn) {
  __shared__ float Ts[D];
  int b = blockIdx.x, h = blockIdx.y, t = threadIdx.x;
  for (int i = t; i < D; i += 256) Ts[i] = T[((size_t)b * H + h) * D + i];
  __syncthreads();
  int col = h * DH + (t >> 2), eq = t & 3;
  float acc = 0.f;
  const float* wp = Wv + (size_t)(eq * 128) * D + col;
  #pragma unroll 8
  for (int e = 0; e < 128; ++e) acc += Ts[eq * 128 + e] * wp[(size_t)e * D];
  acc += __shfl_xor(acc, 1); acc += __shfl_xor(acc, 2);
  if (eq == 0) attn[(size_t)b * D + col] = acc / denom[b * H + h] + bv[col];
}

// ------- x[b,c] = attn[b,:]·Wo[:,c] + bo[c] + ps[b,c]; grid (B,8) -------
__global__ __launch_bounds__(256) void k_x(const float* __restrict__ attn,
                                           const float* __restrict__ Wo,
                                           const float* __restrict__ bo,
                                           const float* __restrict__ ps,
                                           float* __restrict__ x) {
  __shared__ float As[D];
  int b = blockIdx.x, cg = blockIdx.y, t = threadIdx.x;
  for (int i = t; i < D; i += 256) As[i] = attn[(size_t)b * D + i];
  __syncthreads();
  int col = cg * 64 + (t >> 2), eq = t & 3;
  float acc = 0.f;
  const float* wp = Wo + (size_t)(eq * 128) * D + col;
  #pragma unroll 8
  for (int e = 0; e < 128; ++e) acc += As[eq * 128 + e] * wp[(size_t)e * D];
  acc += __shfl_xor(acc, 1); acc += __shfl_xor(acc, 2);
  if (eq == 0) x[(size_t)b * D + col] = acc + bo[col] + ps[(size_t)b * D + col];
}

// ------- fs = LN(x) per row; grid B, 512 thr -------
__global__ __launch_bounds__(512) void k_ln(const float* __restrict__ x,
                                            float* __restrict__ fs) {
  __shared__ float redS[8], redQ[8];
  __shared__ float sM, sI;
  int b = blockIdx.x, t = threadIdx.x;
  float v = x[(size_t)b * D + t];
  float s = v, sq = v * v;
  #pragma unroll
  for (int off = 32; off; off >>= 1) { s += __shfl_xor(s, off); sq += __shfl_xor(sq, off); }
  int wv = t >> 6, ln = t & 63;
  if (ln == 0) { redS[wv] = s; redQ[wv] = sq; }
  __syncthreads();
  if (t == 0) {
    float S = 0.f, Q = 0.f;
    #pragma unroll
    for (int i = 0; i < 8; ++i) { S += redS[i]; Q += redQ[i]; }
    float mean = S * (1.f / D);
    float var = Q * (1.f / D) - mean * mean;
    sM = mean; sI = rsqrtf(var + EPS);
  }
  __syncthreads();
  fs[(size_t)b * D + t] = (v - sM) * sI;
}

// ------- Wgt[c][k] = bf16(Wg[k][c]) -------
__global__ __launch_bounds__(256) void k_prepW(const float* __restrict__ Wg,
                                               ushort* __restrict__ Wgt) {
  __shared__ float tile[32][33];
  int bx = blockIdx.x, by = blockIdx.y;
  int tx = threadIdx.x & 31, ty = threadIdx.x >> 5;  // ty: 0..7
  #pragma unroll
  for (int i = 0; i < 4; ++i)
    tile[ty + i * 8][tx] = Wg[(size_t)(by * 32 + ty + i * 8) * D + bx * 32 + tx];
  __syncthreads();
  #pragma unroll
  for (int i = 0; i < 4; ++i)
    Wgt[(size_t)(bx * 32 + ty + i * 8) * D + by * 32 + tx] = f2bf(tile[tx][ty + i * 8]);
}

// ------- fused: gate = sigmoid(hf@Wg+bg); out = LN(hf + gate*(alpha*fs[fb])) -------
// 64 rows x 512 cols per block, 8 waves; A staged fp32->bf16 in LDS once per K-step
// (double-buffered, pad-40 rows => 2-way-max bank aliasing, free per m136).
__global__ __launch_bounds__(512) void k_gate_ln(const float* __restrict__ hf,
                                                 const ushort* __restrict__ Wgt,
                                                 const float* __restrict__ bg,
                                                 const float* __restrict__ alpha,
                                                 const float* __restrict__ fs,
                                                 const int* __restrict__ fb,
                                                 float* __restrict__ out) {
  __shared__ ushort Asb[2][64][40];  // bf16 A tile, padded stride 40 (80 B)
  __shared__ ushort gls[64][544];    // bf16 gate tile, col-block XOR swizzle
  const int tid = threadIdx.x;
  const int lane = tid & 63, w = tid >> 6;
  const int rowBase = blockIdx.x * 64;
  const int lrow = lane & 15, kg = lane >> 4;

  // A-stage: thread -> (row, k-quad)
  const int arow = tid >> 3, akq = tid & 7;
  const float* Agp = hf + (size_t)(rowBase + arow) * D + akq * 4;
  {
    float4 f = *(const float4*)Agp;
    ushort4v u = { f2bf(f.x), f2bf(f.y), f2bf(f.z), f2bf(f.w) };
    *(ushort4v*)&Asb[0][arow][akq * 4] = u;
  }
  __syncthreads();

  f32x4 acc[4][4] = {};
  const ushort* Bp = Wgt + (size_t)(w * 64 + lrow) * D + kg * 8;

  for (int step = 0; step < 16; ++step) {
    int cur = step & 1;
    if (step < 15) {
      float4 f = *(const float4*)(Agp + (step + 1) * 32);
      ushort4v u = { f2bf(f.x), f2bf(f.y), f2bf(f.z), f2bf(f.w) };
      *(ushort4v*)&Asb[cur ^ 1][arow][akq * 4] = u;
    }
    short8 a[4], bfr[4];
    #pragma unroll
    for (int m = 0; m < 4; ++m)
      a[m] = *(const short8*)&Asb[cur][lrow + m * 16][kg * 8];
    #pragma unroll
    for (int n = 0; n < 4; ++n)
      bfr[n] = *(const short8*)(Bp + (size_t)n * 16 * D + step * 32);
    #pragma unroll
    for (int m = 0; m < 4; ++m)
      #pragma unroll
      for (int n = 0; n < 4; ++n)
        acc[m][n] = __builtin_amdgcn_mfma_f32_16x16x32_bf16(a[m], bfr[n], acc[m][n], 0, 0, 0);
    __syncthreads();
  }

  // phase 1: sigmoid -> swizzled bf16 LDS.  C/D map: col=lane&15, row=(lane>>4)*4+reg
  #pragma unroll
  for (int n = 0; n < 4; ++n) {
    int col = w * 64 + n * 16 + lrow;
    float bgv = bg[col];
    int sblk = (col >> 3) ^ w;
    #pragma unroll
    for (int m = 0; m < 4; ++m) {
      #pragma unroll
      for (int r = 0; r < 4; ++r) {
        int rib = m * 16 + kg * 4 + r;
        float g = fast_sigmoid(acc[m][n][r] + bgv);
        ((ushort*)gls)[rib * 544 + sblk * 8 + (lrow & 7)] = f2bf(g);
      }
    }
  }
  __syncthreads();

  // phase 2: per-row residual + LN, vectorized
  const int row = tid >> 3, cg = tid & 7;      // 8 threads per row, 64 cols each
  const int grow = rowBase + row;
  const int bidx = fb[grow];
  const float* hfr = hf + (size_t)grow * D + cg * 64;
  const float* fsr = fs + (size_t)bidx * D + cg * 64;
  const float* alr = alpha + cg * 64;
  float x[64];
  float s = 0.f, sq = 0.f;
  #pragma unroll
  for (int jb = 0; jb < 8; ++jb) {
    int sblk = (cg * 8 + jb) ^ cg;
    union { ushort8v v; ushort u[8]; } ug;
    ug.v = *(const ushort8v*)((const ushort*)gls + row * 544 + sblk * 8);
    float4 h0 = *(const float4*)(hfr + jb * 8);
    float4 h1 = *(const float4*)(hfr + jb * 8 + 4);
    float4 p0 = *(const float4*)(fsr + jb * 8);
    float4 p1 = *(const float4*)(fsr + jb * 8 + 4);
    float4 a0 = *(const float4*)(alr + jb * 8);
    float4 a1 = *(const float4*)(alr + jb * 8 + 4);
    float hv[8] = {h0.x, h0.y, h0.z, h0.w, h1.x, h1.y, h1.z, h1.w};
    float pv[8] = {p0.x, p0.y, p0.z, p0.w, p1.x, p1.y, p1.z, p1.w};
    float av[8] = {a0.x, a0.y, a0.z, a0.w, a1.x, a1.y, a1.z, a1.w};
    #pragma unroll
    for (int i = 0; i < 8; ++i) {
      float xv = hv[i] + bf2f(ug.u[i]) * (av[i] * pv[i]);
      x[jb * 8 + i] = xv; s += xv; sq += xv * xv;
    }
  }
  #pragma unroll
  for (int off = 1; off < 8; off <<= 1) { s += __shfl_xor(s, off); sq += __shfl_xor(sq, off); }
  float mean = s * (1.f / D);
  float inv = rsqrtf(sq * (1.f / D) - mean * mean + EPS);
  float* op = out + (size_t)grow * D + cg * 64;
  #pragma unroll
  for (int j4 = 0; j4 < 16; ++j4) {
    float4 o = { (x[j4 * 4 + 0] - mean) * inv, (x[j4 * 4 + 1] - mean) * inv,
                 (x[j4 * 4 + 2] - mean) * inv, (x[j4 * 4 + 3] - mean) * inv };
    *(float4*)(op + j4 * 4) = o;
  }
}

extern "C" void kernel_launch(void* const* d_in, const int* in_sizes, int n_in,
                              void* d_out, int out_size, void* d_ws, size_t ws_size,
                              hipStream_t stream) {
  const float* hf    = (const float*)d_in[0];
  const float* ho    = (const float*)d_in[1];
  const float* ps    = (const float*)d_in[2];
  const int*   fb    = (const int*)d_in[3];
  const int*   ob    = (const int*)d_in[4];
  const float* Wq    = (const float*)d_in[5];
  const float* bq    = (const float*)d_in[6];
  const float* Wk    = (const float*)d_in[7];
  const float* bk    = (const float*)d_in[8];
  const float* Wv    = (const float*)d_in[9];
  const float* bv    = (const float*)d_in[10];
  const float* Wo    = (const float*)d_in[11];
  const float* bo    = (const float*)d_in[12];
  const float* Wg    = (const float*)d_in[13];
  const float* bg    = (const float*)d_in[14];
  const float* alpha = (const float*)d_in[15];

  float* out    = (float*)d_out;
  float* fs_out = out + (size_t)NF * D;

  ushort* Wgt   = (ushort*)d_ws;                    // 512KB bf16 Wg^T
  float* ws     = (float*)d_ws + (512 * 512 * 2) / 4;
  float* q      = ws;                      // B*D
  float* Pk     = q + B * D;               // B*H*D
  float* qbk    = Pk + B * H * D;          // B*H
  float* scores = qbk + B * H;             // NT*H
  float* evals  = scores + (size_t)NT * H; // NT*H
  float* denom  = evals + (size_t)NT * H;  // B*H
  float* T      = denom + B * H;           // B*H*D
  float* attn   = T + B * H * D;           // B*D
  float* xbuf   = attn + B * D;            // B*D
  int* fstart   = (int*)(xbuf + B * D);    // B+1
  int* ostart   = fstart + (B + 1);        // B+1

  k_prepW<<<dim3(16, 16), 256, 0, stream>>>(Wg, Wgt);
  k_qproj<<<dim3(B, 8), 256, 0, stream>>>(ps, Wq, bq, q);
  k_pkproj<<<dim3(B, H), 256, 0, stream>>>(q, Wk, bk, Pk, qbk);
  k_bounds<<<1, 256, 0, stream>>>(fb, ob, fstart, ostart);
  hipMemsetAsync(T, 0, (size_t)B * H * D * sizeof(float), stream);
  k_scores<<<NT / 4, 256, 0, stream>>>(hf, ho, fb, ob, Pk, qbk, scores);
  k_segsoftmax<<<B, 512, 0, stream>>>(scores, fstart, ostart, evals, denom);
  k_Taccum<<<dim3(B, 8), 512, 0, stream>>>(hf, ho, fstart, ostart, evals, T);
  k_attn<<<dim3(B, H), 256, 0, stream>>>(T, denom, Wv, bv, attn);
  k_x<<<dim3(B, 8), 256, 0, stream>>>(attn, Wo, bo, ps, xbuf);
  k_ln<<<B, 512, 0, stream>>>(xbuf, fs_out);
  k_gate_ln<<<NF / 64, 512, 0, stream>>>(hf, Wgt, bg, alpha, fs_out, fb, out);
}